// Round 14
// baseline (176.410 us; speedup 1.0000x reference)
//
#include <hip/hip_runtime.h>
#include <hip/hip_bf16.h>
#include <math.h>

// out[b,i,p] = sqrt(yr^2+yi^2); yr/yi = (Hr/Hi[b] @ x[b])*scale + noise*0.01
// B=32, C=256, P=3136. Memory-bound (~290MB HBM -> ~47us floor).
// Round-14 = R12 inner structure (best, 103.7us: permuted-H dense DMA,
// depth-2, counted vmcnt(4), NT noise spread in-loop) made PERSISTENT:
// 768 blocks (3/CU pinned by 48KB LDS) claim tiles via atomicAdd work-
// stealing. Fixes the measured ~1.6 blocks/CU residency / 41% occupancy:
// block cold-start+tail amortized over ~4 tiles, some block per CU is always
// streaming -> HBM duty cycle up.

#define NBATCH 32
#define NC 256
#define NP 3136
#define BM 128
#define BN 64
#define BK 32
#define NBN 49
#define NKI 8          // 256/32 K-steps
#define NTILES (NBATCH * 2 * NBN)   // 3136
#define PGRID 768                   // 3 blocks/CU x 256 CU

typedef __attribute__((ext_vector_type(8))) short short8;
typedef __attribute__((ext_vector_type(4))) float f32x4;

static __device__ __forceinline__ void gload16(const void* g, void* l) {
  __builtin_amdgcn_global_load_lds(
      (const __attribute__((address_space(1))) void*)g,
      (__attribute__((address_space(3))) void*)l, 16, 0, 0);
}

static __device__ __forceinline__ unsigned short bfr(float f) {
  __hip_bfloat16 h = __float2bfloat16(f);   // RNE; pairs into v_cvt_pk_bf16_f32
  return *reinterpret_cast<unsigned short*>(&h);
}

// ---- pre-pass: permute Hr/Hi fp32 -> bf16 ws in LDS-image layout ----
// ws elem idx: (((b2m*8 + kt)*2 + plane)*4096) + fq*1024 + row*8 + e
__global__ __launch_bounds__(256)
void perm_h_kernel(const float* __restrict__ hr, const float* __restrict__ hi,
                   unsigned short* __restrict__ ws)
{
  const int blk   = blockIdx.x;        // b2m*8 + kt  (512 blocks)
  const int kt    = blk & 7;
  const int b2m   = blk >> 3;
  const int plane = threadIdx.x >> 7;  // 0..1
  const int row   = threadIdx.x & 127; // 0..127
  const int b     = b2m >> 1;
  const int bm    = b2m & 1;

  const float* src = (plane ? hi : hr)
      + ((size_t)b * NC + bm * 128 + row) * NC + kt * 32;
  unsigned short* dst = ws + ((size_t)(b2m * 8 + kt) * 2 + plane) * 4096 + row * 8;

  #pragma unroll
  for (int fq = 0; fq < 4; ++fq) {
    const float4 v0 = *reinterpret_cast<const float4*>(src + fq * 8);
    const float4 v1 = *reinterpret_cast<const float4*>(src + fq * 8 + 4);
    union { uint4 v; unsigned short u[8]; } o;
    o.u[0] = bfr(v0.x); o.u[1] = bfr(v0.y); o.u[2] = bfr(v0.z); o.u[3] = bfr(v0.w);
    o.u[4] = bfr(v1.x); o.u[5] = bfr(v1.y); o.u[6] = bfr(v1.z); o.u[7] = bfr(v1.w);
    *reinterpret_cast<uint4*>(dst + fq * 1024) = o.v;
  }
}

// Persistent main. Per-tile inner structure == R12 (verified):
// x LDS fp32 [k][p] with 16B-chunk swizzle (0 conflicts, r2-r13); H LDS bf16
// [fq][row][8] (2-way free); depth-2; per-iter {vmcnt(4 | 0@t0); s_barrier;
// sched_barrier; stage(t+1); 4 NT noise loads; ds_reads; 8 MFMA}.
// FIFO at wait(t>=1): stage(t)[3] | noise(t-1)[4] -> vmcnt(4) retires exactly
// stage(t). Tile boundary: __syncthreads (full drain, once per tile) +
// atomicAdd claim broadcast through LDS.
__global__ __launch_bounds__(512, 6)
void rayleigh_persist(const float* __restrict__ xg,
                      const unsigned short* __restrict__ Hperm,
                      const float* __restrict__ nrg,
                      const float* __restrict__ nig,
                      float* __restrict__ outg,
                      int* __restrict__ counter)
{
  __shared__ float x_lds[2][BK * BN];            // 2 x 8KB
  __shared__ unsigned short hr_lds[2][4096];     // 2 x 8KB  [fq][row][8]
  __shared__ unsigned short hi_lds[2][4096];     // 2 x 8KB
  __shared__ int tile_v;

  const int tid  = threadIdx.x;
  const int lane = tid & 63;
  const int wave = tid >> 6;      // 8 waves: 2(M) x 4(N)
  const int wm   = wave >> 2;
  const int wn   = wave & 3;
  const int fr   = lane & 15;
  const int fq   = lane >> 4;
  const int xork = ((fq & 1) << 6) | ((fq >> 1) << 4);
  const int pcol = ((wn * 16 + fr) << 2) ^ xork;

  while (true) {
    __syncthreads();                      // drain prev tile; protect tile_v/LDS
    if (tid == 0) tile_v = atomicAdd(counter, 1);
    __syncthreads();
    const int v = tile_v;
    if (v >= NTILES) break;

    const int b   = v / 98;
    const int r2  = v - b * 98;
    const int bm  = r2 / 49;
    const int bn  = r2 - bm * 49;

    const float* xsrc   = xg + (size_t)b * NC * NP + (size_t)bn * BN;
    const size_t hpbase = (size_t)((b * 2 + bm) * 8);

    // stage one K-tile: x 8KB (wave w -> chunk w) + H 16KB (wave w -> 2
    // contiguous 1KB chunks from permuted ws). 3 vmem ops/wave.
    auto stage = [&](int t, int buf) {
      {
        const int C16 = wave * 64 + lane;        // 16B chunk idx in 8KB x-tile
        const int k   = C16 >> 4;
        const int cp  = C16 & 15;
        const int fqk = k >> 3;
        const int cl  = cp ^ (((fqk & 1) << 2) | (fqk >> 1));
        const float* src = xsrc + (size_t)(t * BK + k) * NP + cl * 4;
        gload16(src, (char*)x_lds[buf] + wave * 1024);
      }
      #pragma unroll
      for (int i = 0; i < 2; ++i) {
        const int c     = wave * 2 + i;          // 0..15
        const int plane = c >> 3;                // 0=r, 1=i
        const int fqc   = (c >> 1) & 3;
        const int half  = c & 1;
        unsigned short* hl = plane ? hi_lds[buf] : hr_lds[buf];
        const unsigned short* src = Hperm
            + ((hpbase + t) * 2 + plane) * 4096
            + fqc * 1024 + (half * 64 + lane) * 8;   // contiguous per lane
        gload16(src, (char*)hl + fqc * 2048 + half * 1024);
      }
    };

    f32x4 accR[4], accI[4];
    #pragma unroll
    for (int m = 0; m < 4; ++m) {
      accR[m] = (f32x4){0.f, 0.f, 0.f, 0.f};
      accI[m] = (f32x4){0.f, 0.f, 0.f, 0.f};
    }
    float nrv[4][4], niv[4][4];

    const size_t obase = ((size_t)b * NC + bm * BM + wm * 64 + fq * 4) * NP
                       + (size_t)bn * BN + wn * 16 + fr;

    stage(0, 0);

    #pragma unroll
    for (int t = 0; t < NKI; ++t) {
      // counted wait BEFORE barrier (r5/r12-validated ordering)
      if (t == 0) asm volatile("s_waitcnt vmcnt(0)" ::: "memory");
      else        asm volatile("s_waitcnt vmcnt(4)" ::: "memory");
      __builtin_amdgcn_s_barrier();
      __builtin_amdgcn_sched_barrier(0);   // rule #18: no LDS-read hoisting
      if (t + 1 < NKI) stage(t + 1, (t + 1) & 1);

      // noise chunk t: 4 NT dword loads -> regs, used only in epilogue
      {
        const int m = t >> 1, rb = (t & 1) * 2;
        #pragma unroll
        for (int r = 0; r < 2; ++r) {
          const size_t idx = obase + (size_t)(m * 16 + rb + r) * NP;
          nrv[m][rb + r] = __builtin_nontemporal_load(nrg + idx);
          niv[m][rb + r] = __builtin_nontemporal_load(nig + idx);
        }
      }

      // B-fragment: 8 swizzled ds_read_b32 + pk-convert (0 bank conflicts)
      const char* xbuf = (const char*)x_lds[t & 1];
      union { short8 s; unsigned short u[8]; } u;
      #pragma unroll
      for (int j = 0; j < 8; ++j) {
        const float f = *reinterpret_cast<const float*>(xbuf + ((fq * 8 + j) << 8) + pcol);
        u.u[j] = bfr(f);
      }
      const short8 xb = u.s;

      // A-fragments from LDS (ds_read_b128, 2-way = free) + MFMA
      #pragma unroll
      for (int m = 0; m < 4; ++m) {
        const int row = wm * 64 + m * 16 + fr;
        const short8 ar = *reinterpret_cast<const short8*>(&hr_lds[t & 1][fq * 1024 + row * 8]);
        const short8 ai = *reinterpret_cast<const short8*>(&hi_lds[t & 1][fq * 1024 + row * 8]);
        accR[m] = __builtin_amdgcn_mfma_f32_16x16x32_bf16(ar, xb, accR[m], 0, 0, 0);
        accI[m] = __builtin_amdgcn_mfma_f32_16x16x32_bf16(ai, xb, accI[m], 0, 0, 0);
      }
    }

    // ---- epilogue: compute + store (compiler inserts waits for noise regs) --
    const float scale = 0.04419417382415922f;  // 1/sqrt(512)
    const float nstd  = 0.01f;
    #pragma unroll
    for (int m = 0; m < 4; ++m)
      #pragma unroll
      for (int r = 0; r < 4; ++r) {
        const size_t idx = obase + (size_t)(m * 16 + r) * NP;
        const float yr = accR[m][r] * scale + nrv[m][r] * nstd;
        const float yi = accI[m][r] * scale + niv[m][r] * nstd;
        outg[idx] = sqrtf(yr * yr + yi * yi);
      }
  }
}

// fallback (ws too small): R12's PRE=0 self-contained non-persistent path
__global__ __launch_bounds__(512, 4)
void rayleigh_fallback(const float* __restrict__ xg,
                       const float* __restrict__ Hrg,
                       const float* __restrict__ Hig,
                       const float* __restrict__ nrg,
                       const float* __restrict__ nig,
                       float* __restrict__ outg)
{
  __shared__ float x_lds[2][BK * BN];

  const int raw = blockIdx.x;
  const int v   = (raw & 7) * 392 + (raw >> 3);
  const int b   = v / 98;
  const int r2  = v - b * 98;
  const int bm  = r2 / 49;
  const int bn  = r2 - bm * 49;

  const int tid  = threadIdx.x;
  const int lane = tid & 63;
  const int wave = tid >> 6;
  const int wm   = wave >> 2;
  const int wn   = wave & 3;
  const int fr   = lane & 15;
  const int fq   = lane >> 4;

  const float* xsrc = xg + (size_t)b * NC * NP + (size_t)bn * BN;
  const size_t hrowbase = (size_t)b * NC + bm * BM;

  auto stage = [&](int t, int buf) {
    const int C16 = wave * 64 + lane;
    const int k   = C16 >> 4;
    const int cp  = C16 & 15;
    const int fqk = k >> 3;
    const int cl  = cp ^ (((fqk & 1) << 2) | (fqk >> 1));
    gload16(xsrc + (size_t)(t * BK + k) * NP + cl * 4, (char*)x_lds[buf] + wave * 1024);
  };

  f32x4 accR[4], accI[4];
  #pragma unroll
  for (int m = 0; m < 4; ++m) {
    accR[m] = (f32x4){0.f, 0.f, 0.f, 0.f};
    accI[m] = (f32x4){0.f, 0.f, 0.f, 0.f};
  }
  float nrv[4][4], niv[4][4];

  const int xork = ((fq & 1) << 6) | ((fq >> 1) << 4);
  const int pcol = ((wn * 16 + fr) << 2) ^ xork;
  const size_t obase = ((size_t)b * NC + bm * BM + wm * 64 + fq * 4) * NP
                     + (size_t)bn * BN + wn * 16 + fr;

  stage(0, 0);
  for (int t = 0; t < NKI; ++t) {
    __syncthreads();
    if (t + 1 < NKI) stage(t + 1, (t + 1) & 1);
    {
      const int m = t >> 1, rb = (t & 1) * 2;
      #pragma unroll
      for (int r = 0; r < 2; ++r) {
        const size_t idx = obase + (size_t)(m * 16 + rb + r) * NP;
        nrv[m][rb + r] = __builtin_nontemporal_load(nrg + idx);
        niv[m][rb + r] = __builtin_nontemporal_load(nig + idx);
      }
    }
    const char* xbuf = (const char*)x_lds[t & 1];
    union { short8 s; unsigned short u[8]; } u;
    #pragma unroll
    for (int j = 0; j < 8; ++j) {
      const float f = *reinterpret_cast<const float*>(xbuf + ((fq * 8 + j) << 8) + pcol);
      u.u[j] = bfr(f);
    }
    const short8 xb = u.s;
    #pragma unroll
    for (int m = 0; m < 4; ++m) {
      const int row = wm * 64 + m * 16 + fr;
      const float* p1 = Hrg + (hrowbase + row) * NC + t * 32 + fq * 8;
      const float* p2 = Hig + (hrowbase + row) * NC + t * 32 + fq * 8;
      const float4 v0 = *reinterpret_cast<const float4*>(p1);
      const float4 v1 = *reinterpret_cast<const float4*>(p1 + 4);
      const float4 w0 = *reinterpret_cast<const float4*>(p2);
      const float4 w1 = *reinterpret_cast<const float4*>(p2 + 4);
      union { short8 s; unsigned short uu[8]; } a1, a2;
      a1.uu[0] = bfr(v0.x); a1.uu[1] = bfr(v0.y); a1.uu[2] = bfr(v0.z); a1.uu[3] = bfr(v0.w);
      a1.uu[4] = bfr(v1.x); a1.uu[5] = bfr(v1.y); a1.uu[6] = bfr(v1.z); a1.uu[7] = bfr(v1.w);
      a2.uu[0] = bfr(w0.x); a2.uu[1] = bfr(w0.y); a2.uu[2] = bfr(w0.z); a2.uu[3] = bfr(w0.w);
      a2.uu[4] = bfr(w1.x); a2.uu[5] = bfr(w1.y); a2.uu[6] = bfr(w1.z); a2.uu[7] = bfr(w1.w);
      accR[m] = __builtin_amdgcn_mfma_f32_16x16x32_bf16(a1.s, xb, accR[m], 0, 0, 0);
      accI[m] = __builtin_amdgcn_mfma_f32_16x16x32_bf16(a2.s, xb, accI[m], 0, 0, 0);
    }
  }

  const float scale = 0.04419417382415922f;
  const float nstd  = 0.01f;
  #pragma unroll
  for (int m = 0; m < 4; ++m)
    #pragma unroll
    for (int r = 0; r < 4; ++r) {
      const size_t idx = obase + (size_t)(m * 16 + r) * NP;
      const float yr = accR[m][r] * scale + nrv[m][r] * nstd;
      const float yi = accI[m][r] * scale + niv[m][r] * nstd;
      outg[idx] = sqrtf(yr * yr + yi * yi);
    }
}

extern "C" void kernel_launch(void* const* d_in, const int* in_sizes, int n_in,
                              void* d_out, int out_size, void* d_ws, size_t ws_size,
                              hipStream_t stream) {
  const float* x  = (const float*)d_in[0];
  const float* Hr = (const float*)d_in[1];
  const float* Hi = (const float*)d_in[2];
  const float* nr = (const float*)d_in[3];
  const float* ni = (const float*)d_in[4];
  float* out = (float*)d_out;

  const size_t HN      = (size_t)NBATCH * NC * NC;   // elems per H array
  const size_t HPBYTES = HN * 2 * sizeof(unsigned short);  // 8.4 MB

  if (ws_size >= HPBYTES + sizeof(int)) {
    unsigned short* hperm = (unsigned short*)d_ws;
    int* counter = (int*)((char*)d_ws + HPBYTES);
    hipMemsetAsync(counter, 0, sizeof(int), stream);   // stream op: capture-safe
    hipLaunchKernelGGL(perm_h_kernel, dim3(512), dim3(256), 0, stream, Hr, Hi, hperm);
    hipLaunchKernelGGL(rayleigh_persist, dim3(PGRID), dim3(512), 0, stream,
                       x, hperm, nr, ni, out, counter);
  } else {
    hipLaunchKernelGGL(rayleigh_fallback, dim3(NTILES), dim3(512), 0, stream,
                       x, Hr, Hi, nr, ni, out);
  }
}

// Round 15
// 151.260 us; speedup vs baseline: 1.1663x; 1.1663x over previous
//
#include <hip/hip_runtime.h>
#include <hip/hip_bf16.h>
#include <math.h>

// out[b,i,p] = sqrt(yr^2+yi^2); yr/yi = (Hr/Hi[b] @ x[b])*scale + noise*0.01
// B=32, C=256, P=3136. Memory-bound (~290MB HBM -> ~47us floor).
// Round-15 = round-12 BYTE-IDENTICAL (best, 103.7us) + ONE lever:
// __launch_bounds__(512,4) -> (512,6). For 512-thread blocks the 2nd arg w
// gives k = w/2 blocks/CU; R12's own bound capped residency at 2 (measured
// 41% occupancy, ~1.6 blocks/CU) while 48KB LDS permits 3. More resident
// blocks overlap each block's barrier/vmcnt latency exposure. R14 proved the
// XCD bijection is worth ~60us, so locality is preserved exactly.

#define NBATCH 32
#define NC 256
#define NP 3136
#define BM 128
#define BN 64
#define BK 32
#define NBN 49
#define NKI 8          // 256/32 K-steps

typedef __attribute__((ext_vector_type(8))) short short8;
typedef __attribute__((ext_vector_type(4))) float f32x4;

static __device__ __forceinline__ void gload16(const void* g, void* l) {
  __builtin_amdgcn_global_load_lds(
      (const __attribute__((address_space(1))) void*)g,
      (__attribute__((address_space(3))) void*)l, 16, 0, 0);
}

static __device__ __forceinline__ unsigned short bfr(float f) {
  __hip_bfloat16 h = __float2bfloat16(f);   // RNE; pairs into v_cvt_pk_bf16_f32
  return *reinterpret_cast<unsigned short*>(&h);
}

// ---- pre-pass: permute Hr/Hi fp32 -> bf16 ws in LDS-image layout ----
// ws elem idx: (((b2m*8 + kt)*2 + plane)*4096) + fq*1024 + row*8 + e
__global__ __launch_bounds__(256)
void perm_h_kernel(const float* __restrict__ hr, const float* __restrict__ hi,
                   unsigned short* __restrict__ ws)
{
  const int blk   = blockIdx.x;        // b2m*8 + kt  (512 blocks)
  const int kt    = blk & 7;
  const int b2m   = blk >> 3;
  const int plane = threadIdx.x >> 7;  // 0..1
  const int row   = threadIdx.x & 127; // 0..127
  const int b     = b2m >> 1;
  const int bm    = b2m & 1;

  const float* src = (plane ? hi : hr)
      + ((size_t)b * NC + bm * 128 + row) * NC + kt * 32;
  unsigned short* dst = ws + ((size_t)(b2m * 8 + kt) * 2 + plane) * 4096 + row * 8;

  #pragma unroll
  for (int fq = 0; fq < 4; ++fq) {
    const float4 v0 = *reinterpret_cast<const float4*>(src + fq * 8);
    const float4 v1 = *reinterpret_cast<const float4*>(src + fq * 8 + 4);
    union { uint4 v; unsigned short u[8]; } o;
    o.u[0] = bfr(v0.x); o.u[1] = bfr(v0.y); o.u[2] = bfr(v0.z); o.u[3] = bfr(v0.w);
    o.u[4] = bfr(v1.x); o.u[5] = bfr(v1.y); o.u[6] = bfr(v1.z); o.u[7] = bfr(v1.w);
    *reinterpret_cast<uint4*>(dst + fq * 1024) = o.v;
  }
}

// x LDS: fp32 [k 0..31][p 0..63] per buffer, phys 16B-chunk = logical ^
// swz(k>>3) (0 bank conflicts, verified r2-r14). H LDS: bf16 [fq][row][8]
// (2-way = free). Pipeline: depth-2, ONE barrier/iter.
// Counted-vmcnt barrier (PRE=1): per-wave FIFO per iter = stage(t+1)[3] then
// noise(t)[4]. At wait before barrier(t): queue = stage(t)[3] | noise(t-1)[4]
// -> vmcnt(4) retires exactly stage(t); noise floats to its epilogue use.
// t==0: vmcnt(0). Ordering per r5/r12: own-wait BEFORE s_barrier.
// LDS reuse safe: iter t-1 ds_reads are consumed by MFMAs (lgkmcnt) before a
// wave reaches barrier(t); stage(t+1) writes the other buffer post-barrier.
template<int PRE>
__global__ __launch_bounds__(512, 6)
void rayleigh_main(const float* __restrict__ xg,
                   const float* __restrict__ Hrg,
                   const float* __restrict__ Hig,
                   const unsigned short* __restrict__ Hperm,
                   const float* __restrict__ nrg,
                   const float* __restrict__ nig,
                   float* __restrict__ outg)
{
  __shared__ float x_lds[2][BK * BN];            // 2 x 8KB
  __shared__ unsigned short hr_lds[2][4096];     // 2 x 8KB  [fq][row][8]
  __shared__ unsigned short hi_lds[2][4096];     // 2 x 8KB

  // XCD-chunked bijection: 3136 = 8*392. Each XCD owns 4 whole batches.
  const int raw = blockIdx.x;
  const int v   = (raw & 7) * 392 + (raw >> 3);
  const int b   = v / 98;
  const int r2  = v - b * 98;
  const int bm  = r2 / 49;
  const int bn  = r2 - bm * 49;

  const int tid  = threadIdx.x;
  const int lane = tid & 63;
  const int wave = tid >> 6;      // 8 waves: 2(M) x 4(N)
  const int wm   = wave >> 2;
  const int wn   = wave & 3;
  const int fr   = lane & 15;
  const int fq   = lane >> 4;

  const float* xsrc = xg + (size_t)b * NC * NP + (size_t)bn * BN;
  const size_t hrowbase = (size_t)b * NC + bm * BM;
  const size_t hpbase   = (size_t)((b * 2 + bm) * 8);

  // stage one K-tile into buffer `buf`: x 8KB (wave w -> chunk w) + H 16KB
  // (wave w -> 2 contiguous 1KB chunks from permuted ws). 3 vmem ops/wave.
  auto stage = [&](int t, int buf) {
    {
      const int C16 = wave * 64 + lane;          // 16B chunk idx in 8KB x-tile
      const int k   = C16 >> 4;
      const int cp  = C16 & 15;
      const int fqk = k >> 3;
      const int cl  = cp ^ (((fqk & 1) << 2) | (fqk >> 1));
      const float* src = xsrc + (size_t)(t * BK + k) * NP + cl * 4;
      gload16(src, (char*)x_lds[buf] + wave * 1024);
    }
    if constexpr (PRE) {
      #pragma unroll
      for (int i = 0; i < 2; ++i) {
        const int c     = wave * 2 + i;          // 0..15
        const int plane = c >> 3;                // 0=r, 1=i
        const int fqc   = (c >> 1) & 3;
        const int half  = c & 1;
        unsigned short* hl = plane ? hi_lds[buf] : hr_lds[buf];
        const unsigned short* src = Hperm
            + ((hpbase + t) * 2 + plane) * 4096
            + fqc * 1024 + (half * 64 + lane) * 8;   // contiguous per lane
        gload16(src, (char*)hl + fqc * 2048 + half * 1024);
      }
    }
  };

  f32x4 accR[4], accI[4];
  #pragma unroll
  for (int m = 0; m < 4; ++m) {
    accR[m] = (f32x4){0.f, 0.f, 0.f, 0.f};
    accI[m] = (f32x4){0.f, 0.f, 0.f, 0.f};
  }
  float nrv[4][4], niv[4][4];

  const size_t obase = ((size_t)b * NC + bm * BM + wm * 64 + fq * 4) * NP
                     + (size_t)bn * BN + wn * 16 + fr;
  const int xork = ((fq & 1) << 6) | ((fq >> 1) << 4);
  const int pcol = ((wn * 16 + fr) << 2) ^ xork;

  stage(0, 0);

  #pragma unroll
  for (int t = 0; t < NKI; ++t) {
    if constexpr (PRE) {
      // counted wait: retire exactly stage(t); noise(t-1) stays in flight
      if (t == 0) asm volatile("s_waitcnt vmcnt(0)" ::: "memory");
      else        asm volatile("s_waitcnt vmcnt(4)" ::: "memory");
      __builtin_amdgcn_s_barrier();
      __builtin_amdgcn_sched_barrier(0);   // rule #18: no LDS-read hoisting
    } else {
      __syncthreads();
    }
    if (t + 1 < NKI) stage(t + 1, (t + 1) & 1);

    // noise prefetch chunk t: 4 NT dword loads -> regs, used ONLY in epilogue
    {
      const int m = t >> 1, rb = (t & 1) * 2;
      #pragma unroll
      for (int r = 0; r < 2; ++r) {
        const size_t idx = obase + (size_t)(m * 16 + rb + r) * NP;
        nrv[m][rb + r] = __builtin_nontemporal_load(nrg + idx);
        niv[m][rb + r] = __builtin_nontemporal_load(nig + idx);
      }
    }

    // B-fragment: 8 swizzled ds_read_b32 + pk-convert (0 bank conflicts)
    const char* xbuf = (const char*)x_lds[t & 1];
    union { short8 s; unsigned short u[8]; } u;
    #pragma unroll
    for (int j = 0; j < 8; ++j) {
      const float f = *reinterpret_cast<const float*>(xbuf + ((fq * 8 + j) << 8) + pcol);
      u.u[j] = bfr(f);
    }
    const short8 xb = u.s;

    // A-fragments from LDS (ds_read_b128, 2-way = free) + MFMA
    #pragma unroll
    for (int m = 0; m < 4; ++m) {
      const int row = wm * 64 + m * 16 + fr;
      short8 ar, ai;
      if constexpr (PRE) {
        ar = *reinterpret_cast<const short8*>(&hr_lds[t & 1][fq * 1024 + row * 8]);
        ai = *reinterpret_cast<const short8*>(&hi_lds[t & 1][fq * 1024 + row * 8]);
      } else {
        const float* p1 = Hrg + (hrowbase + row) * NC + t * 32 + fq * 8;
        const float* p2 = Hig + (hrowbase + row) * NC + t * 32 + fq * 8;
        const float4 v0 = *reinterpret_cast<const float4*>(p1);
        const float4 v1 = *reinterpret_cast<const float4*>(p1 + 4);
        const float4 w0 = *reinterpret_cast<const float4*>(p2);
        const float4 w1 = *reinterpret_cast<const float4*>(p2 + 4);
        union { short8 s; unsigned short uu[8]; } a1, a2;
        a1.uu[0] = bfr(v0.x); a1.uu[1] = bfr(v0.y); a1.uu[2] = bfr(v0.z); a1.uu[3] = bfr(v0.w);
        a1.uu[4] = bfr(v1.x); a1.uu[5] = bfr(v1.y); a1.uu[6] = bfr(v1.z); a1.uu[7] = bfr(v1.w);
        a2.uu[0] = bfr(w0.x); a2.uu[1] = bfr(w0.y); a2.uu[2] = bfr(w0.z); a2.uu[3] = bfr(w0.w);
        a2.uu[4] = bfr(w1.x); a2.uu[5] = bfr(w1.y); a2.uu[6] = bfr(w1.z); a2.uu[7] = bfr(w1.w);
        ar = a1.s; ai = a2.s;
      }
      accR[m] = __builtin_amdgcn_mfma_f32_16x16x32_bf16(ar, xb, accR[m], 0, 0, 0);
      accI[m] = __builtin_amdgcn_mfma_f32_16x16x32_bf16(ai, xb, accI[m], 0, 0, 0);
    }
  }

  // ---- epilogue: pure compute + store (noise already in regs; compiler
  //      inserts the vmcnt waits for the noise registers' first use) ----
  const float scale = 0.04419417382415922f;  // 1/sqrt(512)
  const float nstd  = 0.01f;
  #pragma unroll
  for (int m = 0; m < 4; ++m)
    #pragma unroll
    for (int r = 0; r < 4; ++r) {
      const size_t idx = obase + (size_t)(m * 16 + r) * NP;
      const float yr = accR[m][r] * scale + nrv[m][r] * nstd;
      const float yi = accI[m][r] * scale + niv[m][r] * nstd;
      outg[idx] = sqrtf(yr * yr + yi * yi);
    }
}

extern "C" void kernel_launch(void* const* d_in, const int* in_sizes, int n_in,
                              void* d_out, int out_size, void* d_ws, size_t ws_size,
                              hipStream_t stream) {
  const float* x  = (const float*)d_in[0];
  const float* Hr = (const float*)d_in[1];
  const float* Hi = (const float*)d_in[2];
  const float* nr = (const float*)d_in[3];
  const float* ni = (const float*)d_in[4];
  float* out = (float*)d_out;

  const size_t HN = (size_t)NBATCH * NC * NC;  // 2,097,152 elems per H array

  if (ws_size >= HN * 2 * sizeof(unsigned short)) {
    unsigned short* hperm = (unsigned short*)d_ws;
    hipLaunchKernelGGL(perm_h_kernel, dim3(512), dim3(256), 0, stream, Hr, Hi, hperm);
    hipLaunchKernelGGL((rayleigh_main<1>), dim3(NBATCH * 2 * NBN), dim3(512), 0, stream,
                       x, Hr, Hi, hperm, nr, ni, out);
  } else {
    hipLaunchKernelGGL((rayleigh_main<0>), dim3(NBATCH * 2 * NBN), dim3(512), 0, stream,
                       x, Hr, Hi, (const unsigned short*)nullptr, nr, ni, out);
  }
}

// Round 16
// 104.114 us; speedup vs baseline: 1.6944x; 1.4528x over previous
//
#include <hip/hip_runtime.h>
#include <hip/hip_bf16.h>
#include <math.h>

// out[b,i,p] = sqrt(yr^2+yi^2); yr/yi = (Hr/Hi[b] @ x[b])*scale + noise*0.01
// B=32, C=256, P=3136. Memory-bound (~290MB HBM -> ~47-63us floor).
// FINAL = Round-12 (verified best: dur 103.7us, dispatch 124.4us).
// Structure: H pre-permuted to bf16 LDS-image in ws (dense DMA staging, kills
// the 8x line-request amplification found in r6); x fp32 DMA double-buffer
// with verified both-sides swizzle (0 bank conflicts); depth-2 pipeline with
// counted-vmcnt barrier (vmcnt(4) retires exactly stage(t), NT noise loads
// float to the epilogue); noise spread across the K-loop (HBM demand
// smoothing); XCD-chunked bijective block swizzle (each XCD owns 4 whole
// batches -> x/H L2-resident; worth ~60us, r14).
// Tested-and-rejected on this base: depth-3 (r8), BM=256 (r9), transposed-
// MFMA float4 IO (r10/r11/r13: ~12% penalty), persistent+work-stealing (r14:
// breaks XCD locality), occupancy 4->6 (r15: L2 partial-line write
// amplification, WRITE 100->182MB).

#define NBATCH 32
#define NC 256
#define NP 3136
#define BM 128
#define BN 64
#define BK 32
#define NBN 49
#define NKI 8          // 256/32 K-steps

typedef __attribute__((ext_vector_type(8))) short short8;
typedef __attribute__((ext_vector_type(4))) float f32x4;

static __device__ __forceinline__ void gload16(const void* g, void* l) {
  __builtin_amdgcn_global_load_lds(
      (const __attribute__((address_space(1))) void*)g,
      (__attribute__((address_space(3))) void*)l, 16, 0, 0);
}

static __device__ __forceinline__ unsigned short bfr(float f) {
  __hip_bfloat16 h = __float2bfloat16(f);   // RNE; pairs into v_cvt_pk_bf16_f32
  return *reinterpret_cast<unsigned short*>(&h);
}

// ---- pre-pass: permute Hr/Hi fp32 -> bf16 ws in LDS-image layout ----
// ws elem idx: (((b2m*8 + kt)*2 + plane)*4096) + fq*1024 + row*8 + e
__global__ __launch_bounds__(256)
void perm_h_kernel(const float* __restrict__ hr, const float* __restrict__ hi,
                   unsigned short* __restrict__ ws)
{
  const int blk   = blockIdx.x;        // b2m*8 + kt  (512 blocks)
  const int kt    = blk & 7;
  const int b2m   = blk >> 3;
  const int plane = threadIdx.x >> 7;  // 0..1
  const int row   = threadIdx.x & 127; // 0..127
  const int b     = b2m >> 1;
  const int bm    = b2m & 1;

  const float* src = (plane ? hi : hr)
      + ((size_t)b * NC + bm * 128 + row) * NC + kt * 32;
  unsigned short* dst = ws + ((size_t)(b2m * 8 + kt) * 2 + plane) * 4096 + row * 8;

  #pragma unroll
  for (int fq = 0; fq < 4; ++fq) {
    const float4 v0 = *reinterpret_cast<const float4*>(src + fq * 8);
    const float4 v1 = *reinterpret_cast<const float4*>(src + fq * 8 + 4);
    union { uint4 v; unsigned short u[8]; } o;
    o.u[0] = bfr(v0.x); o.u[1] = bfr(v0.y); o.u[2] = bfr(v0.z); o.u[3] = bfr(v0.w);
    o.u[4] = bfr(v1.x); o.u[5] = bfr(v1.y); o.u[6] = bfr(v1.z); o.u[7] = bfr(v1.w);
    *reinterpret_cast<uint4*>(dst + fq * 1024) = o.v;
  }
}

// x LDS: fp32 [k 0..31][p 0..63] per buffer, phys 16B-chunk = logical ^
// swz(k>>3) (0 bank conflicts, verified r2-r15). H LDS: bf16 [fq][row][8]
// (2-way = free). Pipeline: depth-2, ONE barrier/iter.
// Counted-vmcnt barrier (PRE=1): per-wave FIFO per iter = stage(t+1)[3] then
// noise(t)[4]. At wait before barrier(t): queue = stage(t)[3] | noise(t-1)[4]
// -> vmcnt(4) retires exactly stage(t); noise floats to its epilogue use.
// t==0: vmcnt(0). Ordering per r5/r12: own-wait BEFORE s_barrier.
// LDS reuse safe: iter t-1 ds_reads are consumed by MFMAs (lgkmcnt) before a
// wave reaches barrier(t); stage(t+1) writes the other buffer post-barrier.
template<int PRE>
__global__ __launch_bounds__(512, 4)
void rayleigh_main(const float* __restrict__ xg,
                   const float* __restrict__ Hrg,
                   const float* __restrict__ Hig,
                   const unsigned short* __restrict__ Hperm,
                   const float* __restrict__ nrg,
                   const float* __restrict__ nig,
                   float* __restrict__ outg)
{
  __shared__ float x_lds[2][BK * BN];            // 2 x 8KB
  __shared__ unsigned short hr_lds[2][4096];     // 2 x 8KB  [fq][row][8]
  __shared__ unsigned short hi_lds[2][4096];     // 2 x 8KB

  // XCD-chunked bijection: 3136 = 8*392. Each XCD owns 4 whole batches.
  const int raw = blockIdx.x;
  const int v   = (raw & 7) * 392 + (raw >> 3);
  const int b   = v / 98;
  const int r2  = v - b * 98;
  const int bm  = r2 / 49;
  const int bn  = r2 - bm * 49;

  const int tid  = threadIdx.x;
  const int lane = tid & 63;
  const int wave = tid >> 6;      // 8 waves: 2(M) x 4(N)
  const int wm   = wave >> 2;
  const int wn   = wave & 3;
  const int fr   = lane & 15;
  const int fq   = lane >> 4;

  const float* xsrc = xg + (size_t)b * NC * NP + (size_t)bn * BN;
  const size_t hrowbase = (size_t)b * NC + bm * BM;
  const size_t hpbase   = (size_t)((b * 2 + bm) * 8);

  // stage one K-tile into buffer `buf`: x 8KB (wave w -> chunk w) + H 16KB
  // (wave w -> 2 contiguous 1KB chunks from permuted ws). 3 vmem ops/wave.
  auto stage = [&](int t, int buf) {
    {
      const int C16 = wave * 64 + lane;          // 16B chunk idx in 8KB x-tile
      const int k   = C16 >> 4;
      const int cp  = C16 & 15;
      const int fqk = k >> 3;
      const int cl  = cp ^ (((fqk & 1) << 2) | (fqk >> 1));
      const float* src = xsrc + (size_t)(t * BK + k) * NP + cl * 4;
      gload16(src, (char*)x_lds[buf] + wave * 1024);
    }
    if constexpr (PRE) {
      #pragma unroll
      for (int i = 0; i < 2; ++i) {
        const int c     = wave * 2 + i;          // 0..15
        const int plane = c >> 3;                // 0=r, 1=i
        const int fqc   = (c >> 1) & 3;
        const int half  = c & 1;
        unsigned short* hl = plane ? hi_lds[buf] : hr_lds[buf];
        const unsigned short* src = Hperm
            + ((hpbase + t) * 2 + plane) * 4096
            + fqc * 1024 + (half * 64 + lane) * 8;   // contiguous per lane
        gload16(src, (char*)hl + fqc * 2048 + half * 1024);
      }
    }
  };

  f32x4 accR[4], accI[4];
  #pragma unroll
  for (int m = 0; m < 4; ++m) {
    accR[m] = (f32x4){0.f, 0.f, 0.f, 0.f};
    accI[m] = (f32x4){0.f, 0.f, 0.f, 0.f};
  }
  float nrv[4][4], niv[4][4];

  const size_t obase = ((size_t)b * NC + bm * BM + wm * 64 + fq * 4) * NP
                     + (size_t)bn * BN + wn * 16 + fr;
  const int xork = ((fq & 1) << 6) | ((fq >> 1) << 4);
  const int pcol = ((wn * 16 + fr) << 2) ^ xork;

  stage(0, 0);

  #pragma unroll
  for (int t = 0; t < NKI; ++t) {
    if constexpr (PRE) {
      // counted wait: retire exactly stage(t); noise(t-1) stays in flight
      if (t == 0) asm volatile("s_waitcnt vmcnt(0)" ::: "memory");
      else        asm volatile("s_waitcnt vmcnt(4)" ::: "memory");
      __builtin_amdgcn_s_barrier();
      __builtin_amdgcn_sched_barrier(0);   // rule #18: no LDS-read hoisting
    } else {
      __syncthreads();
    }
    if (t + 1 < NKI) stage(t + 1, (t + 1) & 1);

    // noise prefetch chunk t: 4 NT dword loads -> regs, used ONLY in epilogue
    {
      const int m = t >> 1, rb = (t & 1) * 2;
      #pragma unroll
      for (int r = 0; r < 2; ++r) {
        const size_t idx = obase + (size_t)(m * 16 + rb + r) * NP;
        nrv[m][rb + r] = __builtin_nontemporal_load(nrg + idx);
        niv[m][rb + r] = __builtin_nontemporal_load(nig + idx);
      }
    }

    // B-fragment: 8 swizzled ds_read_b32 + pk-convert (0 bank conflicts)
    const char* xbuf = (const char*)x_lds[t & 1];
    union { short8 s; unsigned short u[8]; } u;
    #pragma unroll
    for (int j = 0; j < 8; ++j) {
      const float f = *reinterpret_cast<const float*>(xbuf + ((fq * 8 + j) << 8) + pcol);
      u.u[j] = bfr(f);
    }
    const short8 xb = u.s;

    // A-fragments from LDS (ds_read_b128, 2-way = free) + MFMA
    #pragma unroll
    for (int m = 0; m < 4; ++m) {
      const int row = wm * 64 + m * 16 + fr;
      short8 ar, ai;
      if constexpr (PRE) {
        ar = *reinterpret_cast<const short8*>(&hr_lds[t & 1][fq * 1024 + row * 8]);
        ai = *reinterpret_cast<const short8*>(&hi_lds[t & 1][fq * 1024 + row * 8]);
      } else {
        const float* p1 = Hrg + (hrowbase + row) * NC + t * 32 + fq * 8;
        const float* p2 = Hig + (hrowbase + row) * NC + t * 32 + fq * 8;
        const float4 v0 = *reinterpret_cast<const float4*>(p1);
        const float4 v1 = *reinterpret_cast<const float4*>(p1 + 4);
        const float4 w0 = *reinterpret_cast<const float4*>(p2);
        const float4 w1 = *reinterpret_cast<const float4*>(p2 + 4);
        union { short8 s; unsigned short uu[8]; } a1, a2;
        a1.uu[0] = bfr(v0.x); a1.uu[1] = bfr(v0.y); a1.uu[2] = bfr(v0.z); a1.uu[3] = bfr(v0.w);
        a1.uu[4] = bfr(v1.x); a1.uu[5] = bfr(v1.y); a1.uu[6] = bfr(v1.z); a1.uu[7] = bfr(v1.w);
        a2.uu[0] = bfr(w0.x); a2.uu[1] = bfr(w0.y); a2.uu[2] = bfr(w0.z); a2.uu[3] = bfr(w0.w);
        a2.uu[4] = bfr(w1.x); a2.uu[5] = bfr(w1.y); a2.uu[6] = bfr(w1.z); a2.uu[7] = bfr(w1.w);
        ar = a1.s; ai = a2.s;
      }
      accR[m] = __builtin_amdgcn_mfma_f32_16x16x32_bf16(ar, xb, accR[m], 0, 0, 0);
      accI[m] = __builtin_amdgcn_mfma_f32_16x16x32_bf16(ai, xb, accI[m], 0, 0, 0);
    }
  }

  // ---- epilogue: pure compute + store (noise already in regs; compiler
  //      inserts the vmcnt waits for the noise registers' first use) ----
  const float scale = 0.04419417382415922f;  // 1/sqrt(512)
  const float nstd  = 0.01f;
  #pragma unroll
  for (int m = 0; m < 4; ++m)
    #pragma unroll
    for (int r = 0; r < 4; ++r) {
      const size_t idx = obase + (size_t)(m * 16 + r) * NP;
      const float yr = accR[m][r] * scale + nrv[m][r] * nstd;
      const float yi = accI[m][r] * scale + niv[m][r] * nstd;
      outg[idx] = sqrtf(yr * yr + yi * yi);
    }
}

extern "C" void kernel_launch(void* const* d_in, const int* in_sizes, int n_in,
                              void* d_out, int out_size, void* d_ws, size_t ws_size,
                              hipStream_t stream) {
  const float* x  = (const float*)d_in[0];
  const float* Hr = (const float*)d_in[1];
  const float* Hi = (const float*)d_in[2];
  const float* nr = (const float*)d_in[3];
  const float* ni = (const float*)d_in[4];
  float* out = (float*)d_out;

  const size_t HN = (size_t)NBATCH * NC * NC;  // 2,097,152 elems per H array

  if (ws_size >= HN * 2 * sizeof(unsigned short)) {
    unsigned short* hperm = (unsigned short*)d_ws;
    hipLaunchKernelGGL(perm_h_kernel, dim3(512), dim3(256), 0, stream, Hr, Hi, hperm);
    hipLaunchKernelGGL((rayleigh_main<1>), dim3(NBATCH * 2 * NBN), dim3(512), 0, stream,
                       x, Hr, Hi, hperm, nr, ni, out);
  } else {
    hipLaunchKernelGGL((rayleigh_main<0>), dim3(NBATCH * 2 * NBN), dim3(512), 0, stream,
                       x, Hr, Hi, (const unsigned short*)nullptr, nr, ni, out);
  }
}